// Round 1
// baseline (93.883 us; speedup 1.0000x reference)
//
#include <hip/hip_runtime.h>
#include <hip/hip_bf16.h>

typedef __bf16 bf16x8 __attribute__((ext_vector_type(8)));
typedef float  f32x4  __attribute__((ext_vector_type(4)));

constexpr int kD  = 512;
constexpr int kBD = 64;
constexpr int kN  = 4096;
constexpr int kB  = 8;

constexpr int ROWS = 16;   // rows per chunk
constexpr int CPB  = 4;    // chunks per block -> 64 rows/block
constexpr int LDP  = 520;  // padded LDS pitch (bf16 elems): 1040 B rows, 16B aligned, +1 bank-group/row

__device__ inline bf16x8 cvt8(float4 a, float4 b) {
    bf16x8 r;
    r[0] = (__bf16)a.x; r[1] = (__bf16)a.y; r[2] = (__bf16)a.z; r[3] = (__bf16)a.w;
    r[4] = (__bf16)b.x; r[5] = (__bf16)b.y; r[6] = (__bf16)b.z; r[7] = (__bf16)b.w;
    return r;
}

// Computes S[b,j] = sum_n (keys[b,n,:].Wbk[j,:] + bbk[j]) * (values[b,n,:].Wbv[j,:] + bbv[j])
__global__ __launch_bounds__(256, 2)
void lbm_bind(const float* __restrict__ keys, const float* __restrict__ values,
              const float* __restrict__ Wbk,  const float* __restrict__ bbk,
              const float* __restrict__ Wbv,  const float* __restrict__ bbv,
              float* __restrict__ S)
{
    __shared__ __bf16 ldsK[ROWS * LDP];
    __shared__ __bf16 ldsV[ROWS * LDP];

    const int tid = threadIdx.x;
    const int wv  = tid >> 6;      // wave id = j-tile
    const int ln  = tid & 63;
    const int l15 = ln & 15;
    const int lhi = ln >> 4;       // 0..3
    const int jrow = wv * 16 + l15;    // B-operand col -> Wbk/Wbv row j
    const int dk   = lhi * 8;          // k-offset within 32-wide K step

    // ---- preload weight B-fragments (bf16) into registers: 32 frags = 128 VGPR ----
    bf16x8 wk[16], wvv[16];
    #pragma unroll
    for (int d0 = 0; d0 < 16; ++d0) {
        const float* pk = Wbk + jrow * kD + d0 * 32 + dk;
        const float* pv = Wbv + jrow * kD + d0 * 32 + dk;
        float4 a0 = *(const float4*)pk;
        float4 a1 = *(const float4*)(pk + 4);
        float4 b0 = *(const float4*)pv;
        float4 b1 = *(const float4*)(pv + 4);
        wk[d0]  = cvt8(a0, a1);
        wvv[d0] = cvt8(b0, b1);
    }
    const float bk = bbk[jrow];
    const float bv = bbv[jrow];

    float sreg = 0.0f;
    const int blockRow0 = blockIdx.x * (ROWS * CPB);

    for (int it = 0; it < CPB; ++it) {
        const int row0 = blockRow0 + it * ROWS;

        // ---- stage 16 rows of keys & values as bf16 into LDS ----
        // 1024 16B-chunks per array, 4 per thread; loads fully issued before converts.
        float4 kb[8], vb[8];
        #pragma unroll
        for (int s = 0; s < 4; ++s) {
            int c  = tid + s * 256;     // 0..1023
            int r  = c >> 6;            // 64 chunks per row
            int dp = c & 63;
            const float* kp = keys   + (row0 + r) * kD + dp * 8;
            const float* vp = values + (row0 + r) * kD + dp * 8;
            kb[2*s]   = *(const float4*)kp;
            kb[2*s+1] = *(const float4*)(kp + 4);
            vb[2*s]   = *(const float4*)vp;
            vb[2*s+1] = *(const float4*)(vp + 4);
        }
        #pragma unroll
        for (int s = 0; s < 4; ++s) {
            int c  = tid + s * 256;
            int r  = c >> 6;
            int dp = c & 63;
            int off = r * LDP + dp * 8;
            *(bf16x8*)&ldsK[off] = cvt8(kb[2*s], kb[2*s+1]);
            *(bf16x8*)&ldsV[off] = cvt8(vb[2*s], vb[2*s+1]);
        }
        __syncthreads();

        // ---- K-loop: 16 d-steps of 32; wave computes C[16 rows x 16 j] for K and V ----
        f32x4 kacc = {0.f, 0.f, 0.f, 0.f};
        f32x4 vacc = {0.f, 0.f, 0.f, 0.f};
        #pragma unroll
        for (int d0 = 0; d0 < 16; ++d0) {
            int off = l15 * LDP + d0 * 32 + dk;   // A-frag: row = lane&15, 8 contiguous k
            bf16x8 ak = *(const bf16x8*)&ldsK[off];
            bf16x8 av = *(const bf16x8*)&ldsV[off];
            kacc = __builtin_amdgcn_mfma_f32_16x16x32_bf16(ak, wk[d0],  kacc, 0, 0, 0);
            vacc = __builtin_amdgcn_mfma_f32_16x16x32_bf16(av, wvv[d0], vacc, 0, 0, 0);
        }
        // C/D: col j = lane&15, rows = (lane>>4)*4 + i -- rows summed away below
        #pragma unroll
        for (int i = 0; i < 4; ++i)
            sreg += (kacc[i] + bk) * (vacc[i] + bv);

        __syncthreads();   // protect LDS before next stage
    }

    // reduce over the 4 row-groups (lanes ^16, ^32)
    sreg += __shfl_xor(sreg, 16);
    sreg += __shfl_xor(sreg, 32);
    if (lhi == 0) {
        int b = blockRow0 / kN;
        atomicAdd(&S[b * kBD + jrow], sreg);
    }
}

// Tiny epilogue, all f32: S -> Bsum -> t,q -> ms -> ext -> LN -> out
__global__ __launch_bounds__(256)
void lbm_epilogue(const float* __restrict__ S,    const float* __restrict__ query,
                  const float* __restrict__ Wbc,  const float* __restrict__ bbc,
                  const float* __restrict__ Wuq,  const float* __restrict__ buq,
                  const float* __restrict__ Wue,  const float* __restrict__ bue,
                  const float* __restrict__ ln_g, const float* __restrict__ ln_b,
                  const float* __restrict__ Wo,   const float* __restrict__ bo,
                  float* __restrict__ out)
{
    const int b = blockIdx.x;
    const int t = threadIdx.x;

    __shared__ float shS[kBD];
    __shared__ float shB[kD];
    __shared__ float shMs[kBD];
    __shared__ float shN[kD];
    __shared__ float redT[4][kBD];
    __shared__ float redQ[4][kBD];
    __shared__ float redLN[8];
    __shared__ float s_mu, s_rs;

    if (t < kBD) shS[t] = S[b * kBD + t];
    __syncthreads();

    // Bsum[d] = sum_j S[j]*Wbc[d,j] + n*bbc[d]
    for (int d = t; d < kD; d += 256) {
        const float4* wr = (const float4*)(Wbc + d * kBD);
        float acc = 0.f;
        #pragma unroll
        for (int q4 = 0; q4 < 16; ++q4) {
            float4 w = wr[q4];
            acc += w.x * shS[q4*4+0] + w.y * shS[q4*4+1]
                 + w.z * shS[q4*4+2] + w.w * shS[q4*4+3];
        }
        shB[d] = acc + (float)kN * bbc[d];
    }
    __syncthreads();

    // t[jj] = Bsum.Wuq[jj,:] + n*buq ; q[jj] = query.Wuq[jj,:] + buq ; ms = q*t
    {
        const int jj = t & 63, qq = t >> 6;
        const float4* wr = (const float4*)(Wuq + jj * kD + qq * 128);
        const float4* qr = (const float4*)(query + b * kD + qq * 128);
        const float4* br = (const float4*)(shB + qq * 128);
        float at = 0.f, aq = 0.f;
        #pragma unroll
        for (int i = 0; i < 32; ++i) {
            float4 w = wr[i]; float4 bb = br[i]; float4 qv = qr[i];
            at += w.x*bb.x + w.y*bb.y + w.z*bb.z + w.w*bb.w;
            aq += w.x*qv.x + w.y*qv.y + w.z*qv.z + w.w*qv.w;
        }
        redT[qq][jj] = at; redQ[qq][jj] = aq;
    }
    __syncthreads();
    if (t < kBD) {
        float tv = redT[0][t] + redT[1][t] + redT[2][t] + redT[3][t] + (float)kN * buq[t];
        float qv = redQ[0][t] + redQ[1][t] + redQ[2][t] + redQ[3][t] + buq[t];
        shMs[t] = tv * qv;
    }
    __syncthreads();

    // ext[d] = sum_jj ms[jj]*Wue[d,jj] + n*bue[d];  ret = ext/sqrt(n)
    float lsum = 0.f, lsq = 0.f;
    for (int d = t; d < kD; d += 256) {
        const float4* wr = (const float4*)(Wue + d * kBD);
        float acc = 0.f;
        #pragma unroll
        for (int q4 = 0; q4 < 16; ++q4) {
            float4 w = wr[q4];
            acc += w.x * shMs[q4*4+0] + w.y * shMs[q4*4+1]
                 + w.z * shMs[q4*4+2] + w.w * shMs[q4*4+3];
        }
        float ret = (acc + (float)kN * bue[d]) * (1.0f / 64.0f);
        shN[d] = ret;
        lsum += ret; lsq += ret * ret;
    }
    // LayerNorm stats over 512
    #pragma unroll
    for (int m = 1; m < 64; m <<= 1) {
        lsum += __shfl_xor(lsum, m);
        lsq  += __shfl_xor(lsq, m);
    }
    if ((t & 63) == 0) { redLN[t >> 6] = lsum; redLN[4 + (t >> 6)] = lsq; }
    __syncthreads();
    if (t == 0) {
        float s0 = redLN[0] + redLN[1] + redLN[2] + redLN[3];
        float s1 = redLN[4] + redLN[5] + redLN[6] + redLN[7];
        float mu = s0 / (float)kD;
        float var = s1 / (float)kD - mu * mu;
        s_mu = mu;
        s_rs = rsqrtf(var + 1e-5f);
    }
    __syncthreads();
    {
        float mu = s_mu, rs = s_rs;
        for (int d = t; d < kD; d += 256)
            shN[d] = (shN[d] - mu) * rs * ln_g[d] + ln_b[d];
    }
    __syncthreads();

    // out[d] = sum_e shN[e]*Wo[d,e] + bo[d] -- 16-lane groups, coalesced Wo reads
    {
        const int wvi = t >> 6, ln = t & 63;
        const int sub = ln & 15, grp = ln >> 4;
        for (int r = 0; r < 32; ++r) {
            const int d = r * 16 + wvi * 4 + grp;
            const float4* wr = (const float4*)(Wo + d * kD);
            float acc = 0.f;
            #pragma unroll
            for (int i = 0; i < 8; ++i) {
                float4 w  = wr[i * 16 + sub];
                float4 nv = *(const float4*)&shN[i * 64 + sub * 4];
                acc += w.x*nv.x + w.y*nv.y + w.z*nv.z + w.w*nv.w;
            }
            acc += __shfl_xor(acc, 1);
            acc += __shfl_xor(acc, 2);
            acc += __shfl_xor(acc, 4);
            acc += __shfl_xor(acc, 8);
            if (sub == 0) out[b * kD + d] = acc + bo[d];
        }
    }
}

extern "C" void kernel_launch(void* const* d_in, const int* in_sizes, int n_in,
                              void* d_out, int out_size, void* d_ws, size_t ws_size,
                              hipStream_t stream) {
    const float* keys   = (const float*)d_in[0];
    const float* values = (const float*)d_in[1];
    const float* query  = (const float*)d_in[2];
    const float* Wbk    = (const float*)d_in[3];
    const float* bbk    = (const float*)d_in[4];
    const float* Wbv    = (const float*)d_in[5];
    const float* bbv    = (const float*)d_in[6];
    const float* Wbc    = (const float*)d_in[7];
    const float* bbc    = (const float*)d_in[8];
    const float* Wuq    = (const float*)d_in[9];
    const float* buq    = (const float*)d_in[10];
    const float* Wue    = (const float*)d_in[11];
    const float* bue    = (const float*)d_in[12];
    const float* ln_g   = (const float*)d_in[13];
    const float* ln_b   = (const float*)d_in[14];
    const float* Wo     = (const float*)d_in[15];
    const float* bo     = (const float*)d_in[16];

    float* S   = (float*)d_ws;      // [8][64] accumulator
    float* out = (float*)d_out;

    hipMemsetAsync(S, 0, kB * kBD * sizeof(float), stream);

    const int nblocks = (kB * kN) / (ROWS * CPB);   // 512
    lbm_bind<<<dim3(nblocks), dim3(256), 0, stream>>>(keys, values, Wbk, bbk, Wbv, bbv, S);
    lbm_epilogue<<<dim3(kB), dim3(256), 0, stream>>>(S, query, Wbc, bbc, Wuq, buq,
                                                     Wue, bue, ln_g, ln_b, Wo, bo, out);
}

// Round 2
// 64.745 us; speedup vs baseline: 1.4500x; 1.4500x over previous
//
#include <hip/hip_runtime.h>
#include <hip/hip_bf16.h>

typedef __bf16 bf16x8 __attribute__((ext_vector_type(8)));
typedef float  f32x4  __attribute__((ext_vector_type(4)));

constexpr int kD  = 512;
constexpr int kBD = 64;
constexpr int kN  = 4096;
constexpr int kB  = 8;

constexpr int ROWS = 16;   // rows per chunk (MFMA M)
constexpr int CPB  = 4;    // chunks per block -> 64 rows/block -> grid 512

typedef const __attribute__((address_space(1))) void* gas_t;
typedef __attribute__((address_space(3))) void*       las_t;

static __device__ __forceinline__ void gload16(const void* g, void* l) {
    __builtin_amdgcn_global_load_lds((gas_t)g, (las_t)l, 16, 0, 0);
}

__device__ __forceinline__ bf16x8 cvt8(float4 a, float4 b) {
    bf16x8 r;
    r[0] = (__bf16)a.x; r[1] = (__bf16)a.y; r[2] = (__bf16)a.z; r[3] = (__bf16)a.w;
    r[4] = (__bf16)b.x; r[5] = (__bf16)b.y; r[6] = (__bf16)b.z; r[7] = (__bf16)b.w;
    return r;
}

// S[b,j] = sum_n (keys[b,n,:].Wbk[j,:] + bbk[j]) * (values[b,n,:].Wbv[j,:] + bbv[j])
//
// LDS: two 16x512 f32 buffers, linear (global_load_lds). Source granules are
// XOR-pre-swizzled (g' = g ^ (row&7), 16B granules) so fragment ds_read_b128
// spreads 16 rows across 8 bank slots (2-way aliasing = free).
__global__ __launch_bounds__(256, 2)
void lbm_bind(const float* __restrict__ keys, const float* __restrict__ values,
              const float* __restrict__ Wbk,  const float* __restrict__ bbk,
              const float* __restrict__ Wbv,  const float* __restrict__ bbv,
              float* __restrict__ S)
{
    __shared__ float bufK[ROWS * kD];
    __shared__ float bufV[ROWS * kD];

    const int tid = threadIdx.x;
    const int wv  = tid >> 6;
    const int ln  = tid & 63;
    const int l15 = ln & 15;
    const int lhi = ln >> 4;
    const int sw  = l15 & 7;              // row XOR swizzle key
    const int jrow = wv * 16 + l15;       // weight row (j) for B-operand
    const int dk   = lhi * 8;

    const int blockRow0 = blockIdx.x * (ROWS * CPB);

    // ---- stage chunk 0 K immediately (latency hides under weight preload) ----
#define STAGE(buf, src, row0)                                                 \
    {                                                                         \
        _Pragma("unroll")                                                     \
        for (int i = 0; i < 8; ++i) {                                         \
            int p  = i * 256 + tid;       /* 16B granule 0..2047 */           \
            int r  = p >> 7;              /* row 0..15 */                     \
            int gp = p & 127;             /* LDS granule-in-row */            \
            int g  = gp ^ (r & 7);        /* source granule */                \
            gload16((src) + (size_t)((row0) + r) * kD + g * 4, &(buf)[p * 4]);\
        }                                                                     \
    }

    STAGE(bufK, keys, blockRow0);

    // ---- weight B-fragments -> registers (bf16), once per block ----
    bf16x8 wk[16], wvv[16];
    #pragma unroll
    for (int d0 = 0; d0 < 16; ++d0) {
        const float* pk = Wbk + jrow * kD + d0 * 32 + dk;
        const float* pv = Wbv + jrow * kD + d0 * 32 + dk;
        wk[d0]  = cvt8(*(const float4*)pk, *(const float4*)(pk + 4));
        wvv[d0] = cvt8(*(const float4*)pv, *(const float4*)(pv + 4));
    }
    const float bk = bbk[jrow];
    const float bv = bbv[jrow];

    __syncthreads();   // chunk0 K resident

// A-fragment: row = l15, logical k = d0*32 + lhi*8 .. +7 (two swizzled granules)
#define PROJ(buf, W, acc)                                                     \
    {                                                                         \
        _Pragma("unroll")                                                     \
        for (int d0 = 0; d0 < 16; ++d0) {                                     \
            int gc = d0 * 8 + lhi * 2;                                        \
            int o0 = (l15 << 9) + ((gc ^ sw) << 2);                           \
            int o1 = (l15 << 9) + (((gc + 1) ^ sw) << 2);                     \
            float4 a = *(const float4*)&(buf)[o0];                            \
            float4 b = *(const float4*)&(buf)[o1];                            \
            acc = __builtin_amdgcn_mfma_f32_16x16x32_bf16(cvt8(a, b), (W)[d0], acc, 0, 0, 0); \
        }                                                                     \
    }

    float sreg = 0.0f;

    for (int it = 0; it < CPB; ++it) {
        const int row0 = blockRow0 + it * ROWS;

        STAGE(bufV, values, row0);              // V(it) in flight under K-proj
        f32x4 kacc = {0.f, 0.f, 0.f, 0.f};
        PROJ(bufK, wk, kacc);
        __syncthreads();                        // V(it) ready; bufK free

        if (it + 1 < CPB) STAGE(bufK, keys, row0 + ROWS);  // K(it+1) in flight
        f32x4 vacc = {0.f, 0.f, 0.f, 0.f};
        PROJ(bufV, wvv, vacc);

        #pragma unroll
        for (int i = 0; i < 4; ++i)
            sreg += (kacc[i] + bk) * (vacc[i] + bv);

        __syncthreads();                        // K(it+1) ready; bufV free
    }
#undef STAGE
#undef PROJ

    sreg += __shfl_xor(sreg, 16);
    sreg += __shfl_xor(sreg, 32);
    if (lhi == 0) {
        int b = blockRow0 / kN;
        atomicAdd(&S[b * kBD + jrow], sreg);
    }
}

// K2: S -> Bsum -> t,q -> ms -> ext -> LayerNorm -> normed[b][512] (to ws)
__global__ __launch_bounds__(256)
void lbm_mid(const float* __restrict__ S,    const float* __restrict__ query,
             const float* __restrict__ Wbc,  const float* __restrict__ bbc,
             const float* __restrict__ Wuq,  const float* __restrict__ buq,
             const float* __restrict__ Wue,  const float* __restrict__ bue,
             const float* __restrict__ ln_g, const float* __restrict__ ln_b,
             float* __restrict__ normed)
{
    const int b = blockIdx.x;
    const int t = threadIdx.x;

    __shared__ float shS[kBD];
    __shared__ float shB[kD];
    __shared__ float shMs[kBD];
    __shared__ float shN[kD];
    __shared__ float redT[4][kBD];
    __shared__ float redQ[4][kBD];
    __shared__ float redLN[8];
    __shared__ float s_mu, s_rs;

    if (t < kBD) shS[t] = S[b * kBD + t];
    __syncthreads();

    for (int d = t; d < kD; d += 256) {
        const float4* wr = (const float4*)(Wbc + d * kBD);
        float acc = 0.f;
        #pragma unroll
        for (int q4 = 0; q4 < 16; ++q4) {
            float4 w = wr[q4];
            acc += w.x * shS[q4*4+0] + w.y * shS[q4*4+1]
                 + w.z * shS[q4*4+2] + w.w * shS[q4*4+3];
        }
        shB[d] = acc + (float)kN * bbc[d];
    }
    __syncthreads();

    {
        const int jj = t & 63, qq = t >> 6;
        const float4* wr = (const float4*)(Wuq + jj * kD + qq * 128);
        const float4* qr = (const float4*)(query + b * kD + qq * 128);
        const float4* br = (const float4*)(shB + qq * 128);
        float at = 0.f, aq = 0.f;
        #pragma unroll
        for (int i = 0; i < 32; ++i) {
            float4 w = wr[i]; float4 bb = br[i]; float4 qv = qr[i];
            at += w.x*bb.x + w.y*bb.y + w.z*bb.z + w.w*bb.w;
            aq += w.x*qv.x + w.y*qv.y + w.z*qv.z + w.w*qv.w;
        }
        redT[qq][jj] = at; redQ[qq][jj] = aq;
    }
    __syncthreads();
    if (t < kBD) {
        float tv = redT[0][t] + redT[1][t] + redT[2][t] + redT[3][t] + (float)kN * buq[t];
        float qv = redQ[0][t] + redQ[1][t] + redQ[2][t] + redQ[3][t] + buq[t];
        shMs[t] = tv * qv;
    }
    __syncthreads();

    float lsum = 0.f, lsq = 0.f;
    for (int d = t; d < kD; d += 256) {
        const float4* wr = (const float4*)(Wue + d * kBD);
        float acc = 0.f;
        #pragma unroll
        for (int q4 = 0; q4 < 16; ++q4) {
            float4 w = wr[q4];
            acc += w.x * shMs[q4*4+0] + w.y * shMs[q4*4+1]
                 + w.z * shMs[q4*4+2] + w.w * shMs[q4*4+3];
        }
        float ret = (acc + (float)kN * bue[d]) * (1.0f / 64.0f);
        shN[d] = ret;
        lsum += ret; lsq += ret * ret;
    }
    #pragma unroll
    for (int m = 1; m < 64; m <<= 1) {
        lsum += __shfl_xor(lsum, m);
        lsq  += __shfl_xor(lsq, m);
    }
    if ((t & 63) == 0) { redLN[t >> 6] = lsum; redLN[4 + (t >> 6)] = lsq; }
    __syncthreads();
    if (t == 0) {
        float s0 = redLN[0] + redLN[1] + redLN[2] + redLN[3];
        float s1 = redLN[4] + redLN[5] + redLN[6] + redLN[7];
        float mu = s0 / (float)kD;
        float var = s1 / (float)kD - mu * mu;
        s_mu = mu;
        s_rs = rsqrtf(var + 1e-5f);
    }
    __syncthreads();
    {
        float mu = s_mu, rs = s_rs;
        for (int d = t; d < kD; d += 256)
            normed[b * kD + d] = (shN[d] - mu) * rs * ln_g[d] + ln_b[d];
    }
}

// K3: out[b,d] = normed[b,:].Wo[d,:] + bo[d]   -- 64 blocks x 256 threads
__global__ __launch_bounds__(256)
void lbm_out(const float* __restrict__ normed, const float* __restrict__ Wo,
             const float* __restrict__ bo,     float* __restrict__ out)
{
    const int b = blockIdx.x >> 3;
    const int s = blockIdx.x & 7;      // 64-wide output slice
    const int t = threadIdx.x;

    __shared__ float shN[kD];
    shN[t]       = normed[b * kD + t];
    shN[t + 256] = normed[b * kD + t + 256];
    __syncthreads();

    const int d = s * 64 + (t >> 2);   // output index
    const int q = t & 3;               // quarter of the 512-dot
    const float4* wr = (const float4*)(Wo + d * kD + q * 128);
    const float4* nr = (const float4*)(shN + q * 128);
    float acc = 0.f;
    #pragma unroll
    for (int i = 0; i < 32; ++i) {
        float4 w = wr[i]; float4 nv = nr[i];
        acc += w.x*nv.x + w.y*nv.y + w.z*nv.z + w.w*nv.w;
    }
    acc += __shfl_xor(acc, 1);
    acc += __shfl_xor(acc, 2);
    if (q == 0) out[b * kD + d] = acc + bo[d];
}

extern "C" void kernel_launch(void* const* d_in, const int* in_sizes, int n_in,
                              void* d_out, int out_size, void* d_ws, size_t ws_size,
                              hipStream_t stream) {
    const float* keys   = (const float*)d_in[0];
    const float* values = (const float*)d_in[1];
    const float* query  = (const float*)d_in[2];
    const float* Wbk    = (const float*)d_in[3];
    const float* bbk    = (const float*)d_in[4];
    const float* Wbv    = (const float*)d_in[5];
    const float* bbv    = (const float*)d_in[6];
    const float* Wbc    = (const float*)d_in[7];
    const float* bbc    = (const float*)d_in[8];
    const float* Wuq    = (const float*)d_in[9];
    const float* buq    = (const float*)d_in[10];
    const float* Wue    = (const float*)d_in[11];
    const float* bue    = (const float*)d_in[12];
    const float* ln_g   = (const float*)d_in[13];
    const float* ln_b   = (const float*)d_in[14];
    const float* Wo     = (const float*)d_in[15];
    const float* bo     = (const float*)d_in[16];

    float* S      = (float*)d_ws;                 // [8][64]
    float* normed = (float*)d_ws + 512;           // [8][512]
    float* out    = (float*)d_out;

    hipMemsetAsync(S, 0, kB * kBD * sizeof(float), stream);

    const int nblocks = (kB * kN) / (ROWS * CPB);   // 512
    lbm_bind<<<dim3(nblocks), dim3(256), 0, stream>>>(keys, values, Wbk, bbk, Wbv, bbv, S);
    lbm_mid<<<dim3(kB), dim3(256), 0, stream>>>(S, query, Wbc, bbc, Wuq, buq,
                                                Wue, bue, ln_g, ln_b, normed);
    lbm_out<<<dim3(kB * 8), dim3(256), 0, stream>>>(normed, Wo, bo, out);
}